// Round 2
// baseline (3146.730 us; speedup 1.0000x reference)
//
#include <hip/hip_runtime.h>
#include <math.h>

#define N_NODES 100000
#define N_EDGES 500000
#define N_PATHS 3
#define DIM 128
#define K_LAYERS 10

// ---------------- degree histogram, all paths ----------------
__global__ __launch_bounds__(256) void deg_kernel(const int* __restrict__ edges,
                                                  int* __restrict__ degS,
                                                  int* __restrict__ degD) {
    int idx = blockIdx.x * 256 + threadIdx.x;
    if (idx < N_PATHS * N_EDGES) {
        int p = idx / N_EDGES;
        int e = idx - p * N_EDGES;
        const int* src = edges + (size_t)p * 2 * N_EDGES;
        const int* dst = src + N_EDGES;
        atomicAdd(&degS[p * N_NODES + src[e]], 1);
        atomicAdd(&degD[p * N_NODES + dst[e]], 1);
    }
}

// ---------------- normalization factors, all paths ----------------
__global__ __launch_bounds__(256) void norm_kernel(const int* __restrict__ degS,
                                                   const int* __restrict__ degD,
                                                   float* __restrict__ norm_s,
                                                   float* __restrict__ norm_d) {
    int n = blockIdx.x * 256 + threadIdx.x;
    if (n < N_PATHS * N_NODES) {
        norm_s[n] = 1.0f / sqrtf(fmaxf((float)degS[n], 1.0f));
        norm_d[n] = 1.0f / sqrtf(fmaxf((float)degD[n], 1.0f));
    }
}

// ---------------- exclusive scan of in-degrees (one block per path) ----------------
__global__ __launch_bounds__(1024) void scan_kernel(const int* __restrict__ cnt_all,
                                                    int* __restrict__ row_ptr_all,
                                                    int* __restrict__ cursor_all) {
    __shared__ int sums[1024];
    const int n = N_NODES;
    int p = blockIdx.x;
    const int* cnt = cnt_all + (size_t)p * N_NODES;
    int* row_ptr = row_ptr_all + (size_t)p * (N_NODES + 1);
    int* cursor = cursor_all + (size_t)p * N_NODES;
    int t = threadIdx.x;
    int chunk = (n + 1023) / 1024;
    int beg = t * chunk;
    int end = min(beg + chunk, n);
    int s = 0;
    for (int i = beg; i < end; ++i) s += cnt[i];
    sums[t] = s;
    __syncthreads();
    for (int off = 1; off < 1024; off <<= 1) {
        int v = sums[t];
        int add = (t >= off) ? sums[t - off] : 0;
        __syncthreads();
        sums[t] = v + add;
        __syncthreads();
    }
    int prefix = (t == 0) ? 0 : sums[t - 1];
    for (int i = beg; i < end; ++i) {
        row_ptr[i] = prefix;
        cursor[i]  = prefix;
        prefix += cnt[i];
    }
    if (t == 1023) row_ptr[n] = sums[1023];
}

// ---------------- fill CSR: col=src, weight=0.9*norm_s[src]*norm_d[dst] ----------------
__global__ __launch_bounds__(256) void fill_kernel(const int* __restrict__ edges,
                                                   const float* __restrict__ norm_s,
                                                   const float* __restrict__ norm_d,
                                                   int* __restrict__ cursor,
                                                   int2* __restrict__ cw) {
    int idx = blockIdx.x * 256 + threadIdx.x;
    if (idx < N_PATHS * N_EDGES) {
        int p = idx / N_EDGES;
        int e = idx - p * N_EDGES;
        const int* src = edges + (size_t)p * 2 * N_EDGES;
        const int* dst = src + N_EDGES;
        int s = src[e], d = dst[e];
        int pos = atomicAdd(&cursor[p * N_NODES + d], 1);
        float w = 0.9f * norm_s[p * N_NODES + s] * norm_d[p * N_NODES + d];
        cw[(size_t)p * N_EDGES + pos] = make_int2(s, __float_as_int(w));
    }
}

// ---------------- one APPNP layer: pure gather, one 64-lane wave per node ----------------
// lane owns a float2 (128 floats = 64 * float2); edge records preloaded coalesced,
// broadcast by shuffle; 4 gathers in flight per unrolled step.
__global__ __launch_bounds__(256) void prop_kernel(const float2* __restrict__ xsrc,
                                                   const float2* __restrict__ h0,
                                                   float2* __restrict__ xdst,
                                                   const int* __restrict__ row_ptr,
                                                   const int2* __restrict__ cw) {
    int node = blockIdx.x * 4 + (threadIdx.x >> 6);
    int lane = threadIdx.x & 63;
    if (node >= N_NODES) return;
    int beg = row_ptr[node];
    int end = row_ptr[node + 1];
    float2 hv = h0[(size_t)node * 64 + lane];   // prefetch early
    float ax = 0.f, ay = 0.f;
    for (int base = beg; base < end; base += 64) {
        int m = end - base;
        if (m > 64) m = 64;
        int2 e = make_int2(0, 0);
        if (lane < m) e = cw[base + lane];      // one coalesced 512B load per chunk
        int i = 0;
        for (; i + 4 <= m; i += 4) {
            int c0 = __shfl(e.x, i);
            int c1 = __shfl(e.x, i + 1);
            int c2 = __shfl(e.x, i + 2);
            int c3 = __shfl(e.x, i + 3);
            float w0 = __int_as_float(__shfl(e.y, i));
            float w1 = __int_as_float(__shfl(e.y, i + 1));
            float w2 = __int_as_float(__shfl(e.y, i + 2));
            float w3 = __int_as_float(__shfl(e.y, i + 3));
            float2 v0 = xsrc[(size_t)c0 * 64 + lane];
            float2 v1 = xsrc[(size_t)c1 * 64 + lane];
            float2 v2 = xsrc[(size_t)c2 * 64 + lane];
            float2 v3 = xsrc[(size_t)c3 * 64 + lane];
            ax = fmaf(w0, v0.x, ax); ay = fmaf(w0, v0.y, ay);
            ax = fmaf(w1, v1.x, ax); ay = fmaf(w1, v1.y, ay);
            ax = fmaf(w2, v2.x, ax); ay = fmaf(w2, v2.y, ay);
            ax = fmaf(w3, v3.x, ax); ay = fmaf(w3, v3.y, ay);
        }
        for (; i < m; ++i) {
            int c = __shfl(e.x, i);
            float w = __int_as_float(__shfl(e.y, i));
            float2 v = xsrc[(size_t)c * 64 + lane];
            ax = fmaf(w, v.x, ax); ay = fmaf(w, v.y, ay);
        }
    }
    float2 o;
    o.x = ax + 0.1f * hv.x;
    o.y = ay + 0.1f * hv.y;
    xdst[(size_t)node * 64 + lane] = o;
}

__device__ __forceinline__ float fast_tanh(float x) {
    float e = __expf(2.0f * x);
    return 1.0f - 2.0f / (e + 1.0f);   // == (e-1)/(e+1) == tanh(x)
}

// ---------------- attention logits: wsum[p] += sum_n tanh(z_row@W1+b1)@w2 ----------------
// 1024-thread blocks (16 waves; LDS no longer occupancy-binding), 8 rows per wave,
// lane computes hidden cols (lane, lane+64).
__global__ __launch_bounds__(1024) void attn_kernel(const float* __restrict__ z,
                                                    const float* __restrict__ W1,
                                                    const float* __restrict__ b1,
                                                    const float* __restrict__ w2,
                                                    float* __restrict__ wsum) {
    __shared__ float W1s[DIM * DIM];
    for (int i = threadIdx.x; i < DIM * DIM; i += 1024) W1s[i] = W1[i];
    __syncthreads();

    int wid  = threadIdx.x >> 6;    // 0..15
    int lane = threadIdx.x & 63;
    float bias0 = b1[lane], bias1 = b1[lane + 64];
    float wA = w2[lane], wB = w2[lane + 64];
    float acc0 = 0.f, acc1 = 0.f, acc2 = 0.f;
    const int ROWS = N_PATHS * N_NODES;   // 300000; 100000 % 8 == 0 so a tile never crosses paths

    for (int r0 = (blockIdx.x * 16 + wid) * 8; r0 < ROWS; r0 += gridDim.x * 16 * 8) {
        float dA[8], dB[8];
#pragma unroll
        for (int r = 0; r < 8; ++r) { dA[r] = 0.f; dB[r] = 0.f; }
        const float* zr = z + (size_t)r0 * DIM;
        for (int k = 0; k < DIM; k += 4) {
            float4 zv[8];
#pragma unroll
            for (int r = 0; r < 8; ++r) zv[r] = *(const float4*)(zr + r * DIM + k);
#pragma unroll
            for (int kk = 0; kk < 4; ++kk) {
                float w0 = W1s[(k + kk) * DIM + lane];
                float w1 = W1s[(k + kk) * DIM + 64 + lane];
#pragma unroll
                for (int r = 0; r < 8; ++r) {
                    float zk = (kk == 0) ? zv[r].x : (kk == 1) ? zv[r].y
                             : (kk == 2) ? zv[r].z : zv[r].w;
                    dA[r] = fmaf(zk, w0, dA[r]);
                    dB[r] = fmaf(zk, w1, dB[r]);
                }
            }
        }
        float tsum = 0.f;
#pragma unroll
        for (int r = 0; r < 8; ++r) {
            tsum += fast_tanh(dA[r] + bias0) * wA + fast_tanh(dB[r] + bias1) * wB;
        }
#pragma unroll
        for (int off = 32; off; off >>= 1) tsum += __shfl_xor(tsum, off);
        int p = r0 / N_NODES;
        if (p == 0) acc0 += tsum;
        else if (p == 1) acc1 += tsum;
        else acc2 += tsum;
    }
    if (lane == 0) {
        if (acc0 != 0.f) atomicAdd(&wsum[0], acc0);
        if (acc1 != 0.f) atomicAdd(&wsum[1], acc1);
        if (acc2 != 0.f) atomicAdd(&wsum[2], acc2);
    }
}

// ---------------- beta = softmax(wsum / N) over 3 paths ----------------
__global__ void beta_kernel(const float* __restrict__ wsum, float* __restrict__ beta) {
    if (threadIdx.x == 0 && blockIdx.x == 0) {
        float w0 = wsum[0] * (1.0f / N_NODES);
        float w1 = wsum[1] * (1.0f / N_NODES);
        float w2v = wsum[2] * (1.0f / N_NODES);
        float m = fmaxf(w0, fmaxf(w1, w2v));
        float e0 = expf(w0 - m), e1 = expf(w1 - m), e2 = expf(w2v - m);
        float inv = 1.0f / (e0 + e1 + e2);
        beta[0] = e0 * inv;
        beta[1] = e1 * inv;
        beta[2] = e2 * inv;
    }
}

// ---------------- out[n,:] = sum_p beta[p] * z[p,n,:] ----------------
__global__ __launch_bounds__(256) void combine_kernel(const float4* __restrict__ z4,
                                                      const float* __restrict__ beta,
                                                      float4* __restrict__ out4) {
    size_t idx = (size_t)blockIdx.x * 256 + threadIdx.x;
    const size_t M = (size_t)N_NODES * 32;
    if (idx < M) {
        float b0 = beta[0], b1 = beta[1], b2 = beta[2];
        float4 a = z4[idx];
        float4 b = z4[M + idx];
        float4 c = z4[2 * M + idx];
        float4 o;
        o.x = b0 * a.x + b1 * b.x + b2 * c.x;
        o.y = b0 * a.y + b1 * b.y + b2 * c.y;
        o.z = b0 * a.z + b1 * b.z + b2 * c.z;
        o.w = b0 * a.w + b1 * b.w + b2 * c.w;
        out4[idx] = o;
    }
}

extern "C" void kernel_launch(void* const* d_in, const int* in_sizes, int n_in,
                              void* d_out, int out_size, void* d_ws, size_t ws_size,
                              hipStream_t stream) {
    const float* h     = (const float*)d_in[0];
    const int*   edges = (const int*)d_in[1];   // (3, 2, 500000) int32
    const float* W1    = (const float*)d_in[2];
    const float* b1    = (const float*)d_in[3];
    const float* w2    = (const float*)d_in[4];
    float* out = (float*)d_out;

    // ---- workspace carve (8B-aligned) ----
    char* ws = (char*)d_ws;
    float* z = (float*)ws;       ws += (size_t)N_PATHS * N_NODES * DIM * 4;   // 153.6 MB
    float* xb = (float*)ws;      ws += (size_t)N_NODES * DIM * 4;             // 51.2 MB
    int2* cw = (int2*)ws;        ws += (size_t)N_PATHS * N_EDGES * 8;         // 12 MB
    int* row_ptr = (int*)ws;     ws += (size_t)N_PATHS * (N_NODES + 1) * 4 + 8;
    int* cursor = (int*)ws;      ws += (size_t)N_PATHS * N_NODES * 4;
    float* norm_s = (float*)ws;  ws += (size_t)N_PATHS * N_NODES * 4;
    float* norm_d = (float*)ws;  ws += (size_t)N_PATHS * N_NODES * 4;
    int* degS = (int*)ws;        ws += (size_t)N_PATHS * N_NODES * 4;
    int* degD = (int*)ws;        ws += (size_t)N_PATHS * N_NODES * 4;  // adjacent to degS
    float* wsum = (float*)ws;    ws += 4 * 4;
    float* beta = (float*)ws;    ws += 4 * 4;

    // ---- CSR build, all 3 paths batched ----
    hipMemsetAsync(degS, 0, (size_t)2 * N_PATHS * N_NODES * 4, stream);
    deg_kernel<<<(N_PATHS * N_EDGES + 255) / 256, 256, 0, stream>>>(edges, degS, degD);
    norm_kernel<<<(N_PATHS * N_NODES + 255) / 256, 256, 0, stream>>>(degS, degD, norm_s, norm_d);
    scan_kernel<<<N_PATHS, 1024, 0, stream>>>(degD, row_ptr, cursor);
    fill_kernel<<<(N_PATHS * N_EDGES + 255) / 256, 256, 0, stream>>>(edges, norm_s, norm_d, cursor, cw);

    // ---- APPNP propagation, per path (keeps L3 working set ~150 MB) ----
    for (int p = 0; p < N_PATHS; ++p) {
        float* zp = z + (size_t)p * N_NODES * DIM;
        const int* rp = row_ptr + (size_t)p * (N_NODES + 1);
        const int2* cwp = cw + (size_t)p * N_EDGES;
        for (int i = 0; i < K_LAYERS; ++i) {
            // i even -> write xb, i odd -> write zp; layer 9 (last) lands in zp
            const float* s = (i == 0) ? h : ((i & 1) ? xb : zp);
            float* dbuf = (i & 1) ? zp : xb;
            prop_kernel<<<(N_NODES + 3) / 4, 256, 0, stream>>>(
                (const float2*)s, (const float2*)h, (float2*)dbuf, rp, cwp);
        }
    }

    // ---- semantic attention ----
    hipMemsetAsync(wsum, 0, 3 * 4, stream);
    attn_kernel<<<512, 1024, 0, stream>>>(z, W1, b1, w2, wsum);
    beta_kernel<<<1, 64, 0, stream>>>(wsum, beta);
    combine_kernel<<<(N_NODES * 32 + 255) / 256, 256, 0, stream>>>(
        (const float4*)z, beta, (float4*)out);
}

// Round 3
// 3144.891 us; speedup vs baseline: 1.0006x; 1.0006x over previous
//
#include <hip/hip_runtime.h>
#include <math.h>

#define N_NODES 100000
#define N_EDGES 500000
#define N_PATHS 3
#define DIM 128
#define K_LAYERS 10

// ---------------- degree histogram, all paths ----------------
__global__ __launch_bounds__(256) void deg_kernel(const int* __restrict__ edges,
                                                  int* __restrict__ degS,
                                                  int* __restrict__ degD) {
    int idx = blockIdx.x * 256 + threadIdx.x;
    if (idx < N_PATHS * N_EDGES) {
        int p = idx / N_EDGES;
        int e = idx - p * N_EDGES;
        const int* src = edges + (size_t)p * 2 * N_EDGES;
        const int* dst = src + N_EDGES;
        atomicAdd(&degS[p * N_NODES + src[e]], 1);
        atomicAdd(&degD[p * N_NODES + dst[e]], 1);
    }
}

// ---------------- normalization factors, all paths ----------------
__global__ __launch_bounds__(256) void norm_kernel(const int* __restrict__ degS,
                                                   const int* __restrict__ degD,
                                                   float* __restrict__ norm_s,
                                                   float* __restrict__ norm_d) {
    int n = blockIdx.x * 256 + threadIdx.x;
    if (n < N_PATHS * N_NODES) {
        norm_s[n] = 1.0f / sqrtf(fmaxf((float)degS[n], 1.0f));
        norm_d[n] = 1.0f / sqrtf(fmaxf((float)degD[n], 1.0f));
    }
}

// ---------------- exclusive scan of in-degrees (one block per path) ----------------
__global__ __launch_bounds__(1024) void scan_kernel(const int* __restrict__ cnt_all,
                                                    int* __restrict__ row_ptr_all,
                                                    int* __restrict__ cursor_all) {
    __shared__ int sums[1024];
    const int n = N_NODES;
    int p = blockIdx.x;
    const int* cnt = cnt_all + (size_t)p * N_NODES;
    int* row_ptr = row_ptr_all + (size_t)p * (N_NODES + 1);
    int* cursor = cursor_all + (size_t)p * N_NODES;
    int t = threadIdx.x;
    int chunk = (n + 1023) / 1024;
    int beg = t * chunk;
    int end = min(beg + chunk, n);
    int s = 0;
    for (int i = beg; i < end; ++i) s += cnt[i];
    sums[t] = s;
    __syncthreads();
    for (int off = 1; off < 1024; off <<= 1) {
        int v = sums[t];
        int add = (t >= off) ? sums[t - off] : 0;
        __syncthreads();
        sums[t] = v + add;
        __syncthreads();
    }
    int prefix = (t == 0) ? 0 : sums[t - 1];
    for (int i = beg; i < end; ++i) {
        row_ptr[i] = prefix;
        cursor[i]  = prefix;
        prefix += cnt[i];
    }
    if (t == 1023) row_ptr[n] = sums[1023];
}

// ---------------- fill CSR: col=src, weight=0.9*norm_s[src]*norm_d[dst] ----------------
__global__ __launch_bounds__(256) void fill_kernel(const int* __restrict__ edges,
                                                   const float* __restrict__ norm_s,
                                                   const float* __restrict__ norm_d,
                                                   int* __restrict__ cursor,
                                                   int2* __restrict__ cw) {
    int idx = blockIdx.x * 256 + threadIdx.x;
    if (idx < N_PATHS * N_EDGES) {
        int p = idx / N_EDGES;
        int e = idx - p * N_EDGES;
        const int* src = edges + (size_t)p * 2 * N_EDGES;
        const int* dst = src + N_EDGES;
        int s = src[e], d = dst[e];
        int pos = atomicAdd(&cursor[p * N_NODES + d], 1);
        float w = 0.9f * norm_s[p * N_NODES + s] * norm_d[p * N_NODES + d];
        cw[(size_t)p * N_EDGES + pos] = make_int2(s, __float_as_int(w));
    }
}

// ---------------- one APPNP layer: paired-edge float4 gather, one wave per node ----
// lanes 0-31 take even edges, lanes 32-63 take odd edges: each gather instruction
// fetches TWO source rows (2x bytes in flight). Halves combined via shfl_xor(32).
__global__ __launch_bounds__(256) void prop_kernel(const float4* __restrict__ xsrc,
                                                   const float4* __restrict__ h0,
                                                   float4* __restrict__ xdst,
                                                   const int* __restrict__ row_ptr,
                                                   const int2* __restrict__ cw) {
    int node = blockIdx.x * 4 + (threadIdx.x >> 6);
    int lane = threadIdx.x & 63;
    int half = lane >> 5;       // 0: even edge of pair, 1: odd edge
    int col  = lane & 31;       // float4 column within the 128-wide row
    if (node >= N_NODES) return;
    int beg = row_ptr[node];
    int end = row_ptr[node + 1];
    float ax = 0.f, ay = 0.f, az = 0.f, aw = 0.f;

    for (int base = beg; base < end; base += 64) {
        int m = end - base;
        if (m > 64) m = 64;
        int2 e = make_int2(0, 0);
        if (lane < m) e = cw[base + lane];   // coalesced edge-record preload
        int i = 0;
        // 4 pairs (8 edges) in flight
        for (; i + 8 <= m; i += 8) {
            int i0 = i + half, i1 = i + 2 + half, i2 = i + 4 + half, i3 = i + 6 + half;
            int c0 = __shfl(e.x, i0);
            int c1 = __shfl(e.x, i1);
            int c2 = __shfl(e.x, i2);
            int c3 = __shfl(e.x, i3);
            float w0 = __int_as_float(__shfl(e.y, i0));
            float w1 = __int_as_float(__shfl(e.y, i1));
            float w2 = __int_as_float(__shfl(e.y, i2));
            float w3 = __int_as_float(__shfl(e.y, i3));
            float4 v0 = xsrc[(size_t)c0 * 32 + col];
            float4 v1 = xsrc[(size_t)c1 * 32 + col];
            float4 v2 = xsrc[(size_t)c2 * 32 + col];
            float4 v3 = xsrc[(size_t)c3 * 32 + col];
            ax = fmaf(w0, v0.x, ax); ay = fmaf(w0, v0.y, ay);
            az = fmaf(w0, v0.z, az); aw = fmaf(w0, v0.w, aw);
            ax = fmaf(w1, v1.x, ax); ay = fmaf(w1, v1.y, ay);
            az = fmaf(w1, v1.z, az); aw = fmaf(w1, v1.w, aw);
            ax = fmaf(w2, v2.x, ax); ay = fmaf(w2, v2.y, ay);
            az = fmaf(w2, v2.z, az); aw = fmaf(w2, v2.w, aw);
            ax = fmaf(w3, v3.x, ax); ay = fmaf(w3, v3.y, ay);
            az = fmaf(w3, v3.z, az); aw = fmaf(w3, v3.w, aw);
        }
        // tail, one pair (2 edges) per step; odd tail handled by w=0 on upper half
        for (; i < m; i += 2) {
            int idx = i + half;
            int safe = (idx < m) ? idx : i;           // i is always valid (i < m)
            int c = __shfl(e.x, safe);
            float wv = __int_as_float(__shfl(e.y, safe));
            float w = (idx < m) ? wv : 0.f;
            float4 v = xsrc[(size_t)c * 32 + col];
            ax = fmaf(w, v.x, ax); ay = fmaf(w, v.y, ay);
            az = fmaf(w, v.z, az); aw = fmaf(w, v.w, aw);
        }
    }
    // combine even/odd halves (same columns, disjoint edge subsets)
    ax += __shfl_xor(ax, 32);
    ay += __shfl_xor(ay, 32);
    az += __shfl_xor(az, 32);
    aw += __shfl_xor(aw, 32);
    if (half == 0) {
        float4 hv = h0[(size_t)node * 32 + col];
        float4 o;
        o.x = ax + 0.1f * hv.x;
        o.y = ay + 0.1f * hv.y;
        o.z = az + 0.1f * hv.z;
        o.w = aw + 0.1f * hv.w;
        xdst[(size_t)node * 32 + col] = o;
    }
}

__device__ __forceinline__ float fast_tanh(float x) {
    float e = __expf(2.0f * x);
    return 1.0f - 2.0f / (e + 1.0f);   // == (e-1)/(e+1) == tanh(x)
}

// ---------------- attention logits: wsum[p] += sum_n tanh(z_row@W1+b1)@w2 ----------------
// 256-thread blocks (LDS 64KB caps at 2 blocks/CU -> VGPR budget 256, no spill),
// 8 rows per wave for ILP; lane computes hidden cols (lane, lane+64).
__global__ __launch_bounds__(256) void attn_kernel(const float* __restrict__ z,
                                                   const float* __restrict__ W1,
                                                   const float* __restrict__ b1,
                                                   const float* __restrict__ w2,
                                                   float* __restrict__ wsum) {
    __shared__ float W1s[DIM * DIM];
    for (int i = threadIdx.x; i < DIM * DIM; i += 256) W1s[i] = W1[i];
    __syncthreads();

    int wid  = threadIdx.x >> 6;    // 0..3
    int lane = threadIdx.x & 63;
    float bias0 = b1[lane], bias1 = b1[lane + 64];
    float wA = w2[lane], wB = w2[lane + 64];
    float acc0 = 0.f, acc1 = 0.f, acc2 = 0.f;
    const int ROWS = N_PATHS * N_NODES;   // 100000 % 8 == 0 so a tile never crosses paths

    for (int r0 = (blockIdx.x * 4 + wid) * 8; r0 < ROWS; r0 += gridDim.x * 4 * 8) {
        float dA[8], dB[8];
#pragma unroll
        for (int r = 0; r < 8; ++r) { dA[r] = 0.f; dB[r] = 0.f; }
        const float* zr = z + (size_t)r0 * DIM;
        for (int k = 0; k < DIM; k += 4) {
            float4 zv[8];
#pragma unroll
            for (int r = 0; r < 8; ++r) zv[r] = *(const float4*)(zr + r * DIM + k);
#pragma unroll
            for (int kk = 0; kk < 4; ++kk) {
                float w0 = W1s[(k + kk) * DIM + lane];
                float w1 = W1s[(k + kk) * DIM + 64 + lane];
#pragma unroll
                for (int r = 0; r < 8; ++r) {
                    float zk = (kk == 0) ? zv[r].x : (kk == 1) ? zv[r].y
                             : (kk == 2) ? zv[r].z : zv[r].w;
                    dA[r] = fmaf(zk, w0, dA[r]);
                    dB[r] = fmaf(zk, w1, dB[r]);
                }
            }
        }
        float tsum = 0.f;
#pragma unroll
        for (int r = 0; r < 8; ++r) {
            tsum += fast_tanh(dA[r] + bias0) * wA + fast_tanh(dB[r] + bias1) * wB;
        }
#pragma unroll
        for (int off = 32; off; off >>= 1) tsum += __shfl_xor(tsum, off);
        int p = r0 / N_NODES;
        if (p == 0) acc0 += tsum;
        else if (p == 1) acc1 += tsum;
        else acc2 += tsum;
    }
    if (lane == 0) {
        if (acc0 != 0.f) atomicAdd(&wsum[0], acc0);
        if (acc1 != 0.f) atomicAdd(&wsum[1], acc1);
        if (acc2 != 0.f) atomicAdd(&wsum[2], acc2);
    }
}

// ---------------- beta = softmax(wsum / N) over 3 paths ----------------
__global__ void beta_kernel(const float* __restrict__ wsum, float* __restrict__ beta) {
    if (threadIdx.x == 0 && blockIdx.x == 0) {
        float w0 = wsum[0] * (1.0f / N_NODES);
        float w1 = wsum[1] * (1.0f / N_NODES);
        float w2v = wsum[2] * (1.0f / N_NODES);
        float m = fmaxf(w0, fmaxf(w1, w2v));
        float e0 = expf(w0 - m), e1 = expf(w1 - m), e2 = expf(w2v - m);
        float inv = 1.0f / (e0 + e1 + e2);
        beta[0] = e0 * inv;
        beta[1] = e1 * inv;
        beta[2] = e2 * inv;
    }
}

// ---------------- out[n,:] = sum_p beta[p] * z[p,n,:] ----------------
__global__ __launch_bounds__(256) void combine_kernel(const float4* __restrict__ z4,
                                                      const float* __restrict__ beta,
                                                      float4* __restrict__ out4) {
    size_t idx = (size_t)blockIdx.x * 256 + threadIdx.x;
    const size_t M = (size_t)N_NODES * 32;
    if (idx < M) {
        float b0 = beta[0], b1 = beta[1], b2 = beta[2];
        float4 a = z4[idx];
        float4 b = z4[M + idx];
        float4 c = z4[2 * M + idx];
        float4 o;
        o.x = b0 * a.x + b1 * b.x + b2 * c.x;
        o.y = b0 * a.y + b1 * b.y + b2 * c.y;
        o.z = b0 * a.z + b1 * b.z + b2 * c.z;
        o.w = b0 * a.w + b1 * b.w + b2 * c.w;
        out4[idx] = o;
    }
}

extern "C" void kernel_launch(void* const* d_in, const int* in_sizes, int n_in,
                              void* d_out, int out_size, void* d_ws, size_t ws_size,
                              hipStream_t stream) {
    const float* h     = (const float*)d_in[0];
    const int*   edges = (const int*)d_in[1];   // (3, 2, 500000) int32
    const float* W1    = (const float*)d_in[2];
    const float* b1    = (const float*)d_in[3];
    const float* w2    = (const float*)d_in[4];
    float* out = (float*)d_out;

    // ---- workspace carve (8B-aligned) ----
    char* ws = (char*)d_ws;
    float* z = (float*)ws;       ws += (size_t)N_PATHS * N_NODES * DIM * 4;   // 153.6 MB
    float* xb = (float*)ws;      ws += (size_t)N_NODES * DIM * 4;             // 51.2 MB
    int2* cw = (int2*)ws;        ws += (size_t)N_PATHS * N_EDGES * 8;         // 12 MB
    int* row_ptr = (int*)ws;     ws += (size_t)N_PATHS * (N_NODES + 1) * 4 + 8;
    int* cursor = (int*)ws;      ws += (size_t)N_PATHS * N_NODES * 4;
    float* norm_s = (float*)ws;  ws += (size_t)N_PATHS * N_NODES * 4;
    float* norm_d = (float*)ws;  ws += (size_t)N_PATHS * N_NODES * 4;
    int* degS = (int*)ws;        ws += (size_t)N_PATHS * N_NODES * 4;
    int* degD = (int*)ws;        ws += (size_t)N_PATHS * N_NODES * 4;  // adjacent to degS
    float* wsum = (float*)ws;    ws += 4 * 4;
    float* beta = (float*)ws;    ws += 4 * 4;

    // ---- CSR build, all 3 paths batched ----
    hipMemsetAsync(degS, 0, (size_t)2 * N_PATHS * N_NODES * 4, stream);
    deg_kernel<<<(N_PATHS * N_EDGES + 255) / 256, 256, 0, stream>>>(edges, degS, degD);
    norm_kernel<<<(N_PATHS * N_NODES + 255) / 256, 256, 0, stream>>>(degS, degD, norm_s, norm_d);
    scan_kernel<<<N_PATHS, 1024, 0, stream>>>(degD, row_ptr, cursor);
    fill_kernel<<<(N_PATHS * N_EDGES + 255) / 256, 256, 0, stream>>>(edges, norm_s, norm_d, cursor, cw);

    // ---- APPNP propagation, per path (keeps L3 working set ~150 MB) ----
    for (int p = 0; p < N_PATHS; ++p) {
        float* zp = z + (size_t)p * N_NODES * DIM;
        const int* rp = row_ptr + (size_t)p * (N_NODES + 1);
        const int2* cwp = cw + (size_t)p * N_EDGES;
        for (int i = 0; i < K_LAYERS; ++i) {
            // i even -> write xb, i odd -> write zp; layer 9 (last) lands in zp
            const float* s = (i == 0) ? h : ((i & 1) ? xb : zp);
            float* dbuf = (i & 1) ? zp : xb;
            prop_kernel<<<(N_NODES + 3) / 4, 256, 0, stream>>>(
                (const float4*)s, (const float4*)h, (float4*)dbuf, rp, cwp);
        }
    }

    // ---- semantic attention ----
    hipMemsetAsync(wsum, 0, 3 * 4, stream);
    attn_kernel<<<1024, 256, 0, stream>>>(z, W1, b1, w2, wsum);
    beta_kernel<<<1, 64, 0, stream>>>(wsum, beta);
    combine_kernel<<<(N_NODES * 32 + 255) / 256, 256, 0, stream>>>(
        (const float4*)z, beta, (float4*)out);
}

// Round 4
// 2167.532 us; speedup vs baseline: 1.4518x; 1.4509x over previous
//
#include <hip/hip_runtime.h>
#include <math.h>

#define N_NODES 100000
#define N_EDGES 500000
#define N_PATHS 3
#define DIM 128
#define K_LAYERS 10

// ---------------- degree histogram, all paths ----------------
__global__ __launch_bounds__(256) void deg_kernel(const int* __restrict__ edges,
                                                  int* __restrict__ degS,
                                                  int* __restrict__ degD) {
    int idx = blockIdx.x * 256 + threadIdx.x;
    if (idx < N_PATHS * N_EDGES) {
        int p = idx / N_EDGES;
        int e = idx - p * N_EDGES;
        const int* src = edges + (size_t)p * 2 * N_EDGES;
        const int* dst = src + N_EDGES;
        atomicAdd(&degS[p * N_NODES + src[e]], 1);
        atomicAdd(&degD[p * N_NODES + dst[e]], 1);
    }
}

// ---------------- normalization factors, all paths ----------------
__global__ __launch_bounds__(256) void norm_kernel(const int* __restrict__ degS,
                                                   const int* __restrict__ degD,
                                                   float* __restrict__ norm_s,
                                                   float* __restrict__ norm_d) {
    int n = blockIdx.x * 256 + threadIdx.x;
    if (n < N_PATHS * N_NODES) {
        norm_s[n] = 1.0f / sqrtf(fmaxf((float)degS[n], 1.0f));
        norm_d[n] = 1.0f / sqrtf(fmaxf((float)degD[n], 1.0f));
    }
}

// ---------------- exclusive scan of in-degrees (one block per path) ----------------
__global__ __launch_bounds__(1024) void scan_kernel(const int* __restrict__ cnt_all,
                                                    int* __restrict__ row_ptr_all,
                                                    int* __restrict__ cursor_all) {
    __shared__ int sums[1024];
    const int n = N_NODES;
    int p = blockIdx.x;
    const int* cnt = cnt_all + (size_t)p * N_NODES;
    int* row_ptr = row_ptr_all + (size_t)p * (N_NODES + 1);
    int* cursor = cursor_all + (size_t)p * N_NODES;
    int t = threadIdx.x;
    int chunk = (n + 1023) / 1024;
    int beg = t * chunk;
    int end = min(beg + chunk, n);
    int s = 0;
    for (int i = beg; i < end; ++i) s += cnt[i];
    sums[t] = s;
    __syncthreads();
    for (int off = 1; off < 1024; off <<= 1) {
        int v = sums[t];
        int add = (t >= off) ? sums[t - off] : 0;
        __syncthreads();
        sums[t] = v + add;
        __syncthreads();
    }
    int prefix = (t == 0) ? 0 : sums[t - 1];
    for (int i = beg; i < end; ++i) {
        row_ptr[i] = prefix;
        cursor[i]  = prefix;
        prefix += cnt[i];
    }
    if (t == 1023) row_ptr[n] = sums[1023];
}

// ---------------- fill CSR: col=src, weight=0.9*norm_s[src]*norm_d[dst] ----------------
__global__ __launch_bounds__(256) void fill_kernel(const int* __restrict__ edges,
                                                   const float* __restrict__ norm_s,
                                                   const float* __restrict__ norm_d,
                                                   int* __restrict__ cursor,
                                                   int2* __restrict__ cw) {
    int idx = blockIdx.x * 256 + threadIdx.x;
    if (idx < N_PATHS * N_EDGES) {
        int p = idx / N_EDGES;
        int e = idx - p * N_EDGES;
        const int* src = edges + (size_t)p * 2 * N_EDGES;
        const int* dst = src + N_EDGES;
        int s = src[e], d = dst[e];
        int pos = atomicAdd(&cursor[p * N_NODES + d], 1);
        float w = 0.9f * norm_s[p * N_NODES + s] * norm_d[p * N_NODES + d];
        cw[(size_t)p * N_EDGES + pos] = make_int2(s, __float_as_int(w));
    }
}

// ---------------- one APPNP layer: quarter-wave per edge (4 edges in flight) -----
// lane = qid*16 + ql: qid in 0..3 selects edge-of-group, ql owns float4 slots
// {ql, ql+16} of the 32-float4 row. Quarters reduced via shfl_xor(16),(32).
__global__ __launch_bounds__(256) void prop_kernel(const float4* __restrict__ xsrc,
                                                   const float4* __restrict__ h0,
                                                   float4* __restrict__ xdst,
                                                   const int* __restrict__ row_ptr,
                                                   const int2* __restrict__ cw) {
    int node = blockIdx.x * 4 + (threadIdx.x >> 6);
    int lane = threadIdx.x & 63;
    int qid  = lane >> 4;       // edge slot within 4-edge group
    int ql   = lane & 15;       // float4 column (low half)
    if (node >= N_NODES) return;
    int beg = row_ptr[node];
    int m = row_ptr[node + 1] - beg;
    float4 hv = make_float4(0.f, 0.f, 0.f, 0.f);
    if (lane < 32) hv = h0[(size_t)node * 32 + lane];   // slot == lane for lane<32
    float4 a0 = make_float4(0.f, 0.f, 0.f, 0.f);
    float4 a1 = make_float4(0.f, 0.f, 0.f, 0.f);

    for (int base = 0; base < m; base += 64) {
        int mm = m - base;
        if (mm > 64) mm = 64;
        int2 e = make_int2(0, 0);
        if (lane < mm) e = cw[beg + base + lane];   // coalesced edge-record preload
        for (int i = 0; i < mm; i += 8) {
            int iA = i + qid;
            int iB = i + 4 + qid;
            int iAs = (iA < mm) ? iA : 0;
            int iBs = (iB < mm) ? iB : 0;
            // broadcasts executed by all lanes (sources always active)
            int   cA = __shfl(e.x, iAs);
            int   cB = __shfl(e.x, iBs);
            float wA = __int_as_float(__shfl(e.y, iAs));
            float wB = __int_as_float(__shfl(e.y, iBs));
            if (iA < mm) {   // exec-masked: no wasted fetch on ragged tail
                float4 v0 = xsrc[(size_t)cA * 32 + ql];
                float4 v1 = xsrc[(size_t)cA * 32 + 16 + ql];
                a0.x = fmaf(wA, v0.x, a0.x); a0.y = fmaf(wA, v0.y, a0.y);
                a0.z = fmaf(wA, v0.z, a0.z); a0.w = fmaf(wA, v0.w, a0.w);
                a1.x = fmaf(wA, v1.x, a1.x); a1.y = fmaf(wA, v1.y, a1.y);
                a1.z = fmaf(wA, v1.z, a1.z); a1.w = fmaf(wA, v1.w, a1.w);
            }
            if (iB < mm) {
                float4 v0 = xsrc[(size_t)cB * 32 + ql];
                float4 v1 = xsrc[(size_t)cB * 32 + 16 + ql];
                a0.x = fmaf(wB, v0.x, a0.x); a0.y = fmaf(wB, v0.y, a0.y);
                a0.z = fmaf(wB, v0.z, a0.z); a0.w = fmaf(wB, v0.w, a0.w);
                a1.x = fmaf(wB, v1.x, a1.x); a1.y = fmaf(wB, v1.y, a1.y);
                a1.z = fmaf(wB, v1.z, a1.z); a1.w = fmaf(wB, v1.w, a1.w);
            }
        }
    }
    // reduce over the 4 quarters (lanes ql, ql+16, ql+32, ql+48)
#pragma unroll
    for (int off = 16; off <= 32; off <<= 1) {
        a0.x += __shfl_xor(a0.x, off); a0.y += __shfl_xor(a0.y, off);
        a0.z += __shfl_xor(a0.z, off); a0.w += __shfl_xor(a0.w, off);
        a1.x += __shfl_xor(a1.x, off); a1.y += __shfl_xor(a1.y, off);
        a1.z += __shfl_xor(a1.z, off); a1.w += __shfl_xor(a1.w, off);
    }
    if (lane < 32) {
        float4 acc = (lane < 16) ? a0 : a1;   // slot == lane
        float4 o;
        o.x = acc.x + 0.1f * hv.x;
        o.y = acc.y + 0.1f * hv.y;
        o.z = acc.z + 0.1f * hv.z;
        o.w = acc.w + 0.1f * hv.w;
        xdst[(size_t)node * 32 + lane] = o;
    }
}

__device__ __forceinline__ float fast_tanh(float x) {
    float e = __expf(2.0f * x);
    return 1.0f - 2.0f / (e + 1.0f);   // == (e-1)/(e+1) == tanh(x)
}

// ---------------- attention logits: wsum[p] += sum_n tanh(z_row@W1+b1)@w2 ----------------
// Per-wave 8-row z tile staged in private LDS slot via coalesced float4 loads,
// pipelined one tile ahead in registers. Lane owns 4 rows (rh half) x 4 cols (c4).
// LDS: W1 64KB + 4x4KB tiles = 80KB -> 2 blocks/CU.
__global__ __launch_bounds__(256) void attn_kernel(const float* __restrict__ z,
                                                   const float* __restrict__ W1,
                                                   const float* __restrict__ b1,
                                                   const float* __restrict__ w2,
                                                   float* __restrict__ wsum) {
    __shared__ float W1s[DIM * DIM];        // 64 KB
    __shared__ float zt[4][8 * DIM];        // 16 KB, one 8-row tile per wave
    for (int i = threadIdx.x; i < DIM * DIM; i += 256) W1s[i] = W1[i];
    __syncthreads();

    const int wid  = threadIdx.x >> 6;      // 0..3
    const int lane = threadIdx.x & 63;
    const int c4 = (lane & 31) * 4;         // 4-column group base
    const int rh = lane >> 5;               // row half: rows rh*4 .. rh*4+3
    float* myz = zt[wid];

    float4 bias = *(const float4*)(b1 + c4);
    float4 wv   = *(const float4*)(w2 + c4);

    float accP0 = 0.f, accP1 = 0.f, accP2 = 0.f;
    const int NTILES = N_PATHS * N_NODES / 8;   // 37500
    const int TPP = N_NODES / 8;                // 12500 tiles per path
    const int tstride = gridDim.x * 4;

    int t = blockIdx.x * 4 + wid;
    float4 pre0, pre1, pre2, pre3;
    if (t < NTILES) {
        const float4* g = (const float4*)(z + (size_t)t * 8 * DIM);
        pre0 = g[lane]; pre1 = g[64 + lane]; pre2 = g[128 + lane]; pre3 = g[192 + lane];
    }
    for (; t < NTILES; t += tstride) {
        // write current tile to this wave's LDS slot (compiler waits vmcnt for pre*)
        *(float4*)&myz[lane * 4]              = pre0;
        *(float4*)&myz[(64 + lane) * 4]       = pre1;
        *(float4*)&myz[(128 + lane) * 4]      = pre2;
        *(float4*)&myz[(192 + lane) * 4]      = pre3;
        asm volatile("s_waitcnt lgkmcnt(0)" ::: "memory");
        // prefetch next tile into registers (hidden under compute)
        int tn = t + tstride;
        if (tn < NTILES) {
            const float4* g = (const float4*)(z + (size_t)tn * 8 * DIM);
            pre0 = g[lane]; pre1 = g[64 + lane]; pre2 = g[128 + lane]; pre3 = g[192 + lane];
        }
        // compute: 4 rows x 4 cols per lane
        float acc[4][4];
#pragma unroll
        for (int r = 0; r < 4; ++r)
#pragma unroll
            for (int j = 0; j < 4; ++j) acc[r][j] = 0.f;

        for (int k = 0; k < DIM; k += 4) {
            float4 w0 = *(const float4*)&W1s[(k + 0) * DIM + c4];
            float4 w1_ = *(const float4*)&W1s[(k + 1) * DIM + c4];
            float4 w2_ = *(const float4*)&W1s[(k + 2) * DIM + c4];
            float4 w3_ = *(const float4*)&W1s[(k + 3) * DIM + c4];
#pragma unroll
            for (int r = 0; r < 4; ++r) {
                float4 zv = *(const float4*)&myz[(rh * 4 + r) * DIM + k];
                acc[r][0] = fmaf(zv.x, w0.x, acc[r][0]);
                acc[r][1] = fmaf(zv.x, w0.y, acc[r][1]);
                acc[r][2] = fmaf(zv.x, w0.z, acc[r][2]);
                acc[r][3] = fmaf(zv.x, w0.w, acc[r][3]);
                acc[r][0] = fmaf(zv.y, w1_.x, acc[r][0]);
                acc[r][1] = fmaf(zv.y, w1_.y, acc[r][1]);
                acc[r][2] = fmaf(zv.y, w1_.z, acc[r][2]);
                acc[r][3] = fmaf(zv.y, w1_.w, acc[r][3]);
                acc[r][0] = fmaf(zv.z, w2_.x, acc[r][0]);
                acc[r][1] = fmaf(zv.z, w2_.y, acc[r][1]);
                acc[r][2] = fmaf(zv.z, w2_.z, acc[r][2]);
                acc[r][3] = fmaf(zv.z, w2_.w, acc[r][3]);
                acc[r][0] = fmaf(zv.w, w3_.x, acc[r][0]);
                acc[r][1] = fmaf(zv.w, w3_.y, acc[r][1]);
                acc[r][2] = fmaf(zv.w, w3_.z, acc[r][2]);
                acc[r][3] = fmaf(zv.w, w3_.w, acc[r][3]);
            }
        }
        // epilogue: tanh + dot(w2) + full-wave reduce
        float psum = 0.f;
#pragma unroll
        for (int r = 0; r < 4; ++r) {
            psum += fast_tanh(acc[r][0] + bias.x) * wv.x;
            psum += fast_tanh(acc[r][1] + bias.y) * wv.y;
            psum += fast_tanh(acc[r][2] + bias.z) * wv.z;
            psum += fast_tanh(acc[r][3] + bias.w) * wv.w;
        }
#pragma unroll
        for (int off = 32; off; off >>= 1) psum += __shfl_xor(psum, off);
        if (lane == 0) {
            int p = t / TPP;
            if (p == 0) accP0 += psum;
            else if (p == 1) accP1 += psum;
            else accP2 += psum;
        }
    }
    if (lane == 0) {
        if (accP0 != 0.f) atomicAdd(&wsum[0], accP0);
        if (accP1 != 0.f) atomicAdd(&wsum[1], accP1);
        if (accP2 != 0.f) atomicAdd(&wsum[2], accP2);
    }
}

// ---------------- beta = softmax(wsum / N) over 3 paths ----------------
__global__ void beta_kernel(const float* __restrict__ wsum, float* __restrict__ beta) {
    if (threadIdx.x == 0 && blockIdx.x == 0) {
        float w0 = wsum[0] * (1.0f / N_NODES);
        float w1 = wsum[1] * (1.0f / N_NODES);
        float w2v = wsum[2] * (1.0f / N_NODES);
        float m = fmaxf(w0, fmaxf(w1, w2v));
        float e0 = expf(w0 - m), e1 = expf(w1 - m), e2 = expf(w2v - m);
        float inv = 1.0f / (e0 + e1 + e2);
        beta[0] = e0 * inv;
        beta[1] = e1 * inv;
        beta[2] = e2 * inv;
    }
}

// ---------------- out[n,:] = sum_p beta[p] * z[p,n,:] ----------------
__global__ __launch_bounds__(256) void combine_kernel(const float4* __restrict__ z4,
                                                      const float* __restrict__ beta,
                                                      float4* __restrict__ out4) {
    size_t idx = (size_t)blockIdx.x * 256 + threadIdx.x;
    const size_t M = (size_t)N_NODES * 32;
    if (idx < M) {
        float b0 = beta[0], b1 = beta[1], b2 = beta[2];
        float4 a = z4[idx];
        float4 b = z4[M + idx];
        float4 c = z4[2 * M + idx];
        float4 o;
        o.x = b0 * a.x + b1 * b.x + b2 * c.x;
        o.y = b0 * a.y + b1 * b.y + b2 * c.y;
        o.z = b0 * a.z + b1 * b.z + b2 * c.z;
        o.w = b0 * a.w + b1 * b.w + b2 * c.w;
        out4[idx] = o;
    }
}

extern "C" void kernel_launch(void* const* d_in, const int* in_sizes, int n_in,
                              void* d_out, int out_size, void* d_ws, size_t ws_size,
                              hipStream_t stream) {
    const float* h     = (const float*)d_in[0];
    const int*   edges = (const int*)d_in[1];   // (3, 2, 500000) int32
    const float* W1    = (const float*)d_in[2];
    const float* b1    = (const float*)d_in[3];
    const float* w2    = (const float*)d_in[4];
    float* out = (float*)d_out;

    // ---- workspace carve (8B-aligned) ----
    char* ws = (char*)d_ws;
    float* z = (float*)ws;       ws += (size_t)N_PATHS * N_NODES * DIM * 4;   // 153.6 MB
    float* xb = (float*)ws;      ws += (size_t)N_NODES * DIM * 4;             // 51.2 MB
    int2* cw = (int2*)ws;        ws += (size_t)N_PATHS * N_EDGES * 8;         // 12 MB
    int* row_ptr = (int*)ws;     ws += (size_t)N_PATHS * (N_NODES + 1) * 4 + 8;
    int* cursor = (int*)ws;      ws += (size_t)N_PATHS * N_NODES * 4;
    float* norm_s = (float*)ws;  ws += (size_t)N_PATHS * N_NODES * 4;
    float* norm_d = (float*)ws;  ws += (size_t)N_PATHS * N_NODES * 4;
    int* degS = (int*)ws;        ws += (size_t)N_PATHS * N_NODES * 4;
    int* degD = (int*)ws;        ws += (size_t)N_PATHS * N_NODES * 4;  // adjacent to degS
    float* wsum = (float*)ws;    ws += 4 * 4;
    float* beta = (float*)ws;    ws += 4 * 4;

    // ---- CSR build, all 3 paths batched ----
    hipMemsetAsync(degS, 0, (size_t)2 * N_PATHS * N_NODES * 4, stream);
    deg_kernel<<<(N_PATHS * N_EDGES + 255) / 256, 256, 0, stream>>>(edges, degS, degD);
    norm_kernel<<<(N_PATHS * N_NODES + 255) / 256, 256, 0, stream>>>(degS, degD, norm_s, norm_d);
    scan_kernel<<<N_PATHS, 1024, 0, stream>>>(degD, row_ptr, cursor);
    fill_kernel<<<(N_PATHS * N_EDGES + 255) / 256, 256, 0, stream>>>(edges, norm_s, norm_d, cursor, cw);

    // ---- APPNP propagation, per path (keeps L3 working set ~150 MB) ----
    for (int p = 0; p < N_PATHS; ++p) {
        float* zp = z + (size_t)p * N_NODES * DIM;
        const int* rp = row_ptr + (size_t)p * (N_NODES + 1);
        const int2* cwp = cw + (size_t)p * N_EDGES;
        for (int i = 0; i < K_LAYERS; ++i) {
            // i even -> write xb, i odd -> write zp; layer 9 (last) lands in zp
            const float* s = (i == 0) ? h : ((i & 1) ? xb : zp);
            float* dbuf = (i & 1) ? zp : xb;
            prop_kernel<<<(N_NODES + 3) / 4, 256, 0, stream>>>(
                (const float4*)s, (const float4*)h, (float4*)dbuf, rp, cwp);
        }
    }

    // ---- semantic attention ----
    hipMemsetAsync(wsum, 0, 3 * 4, stream);
    attn_kernel<<<1024, 256, 0, stream>>>(z, W1, b1, w2, wsum);
    beta_kernel<<<1, 64, 0, stream>>>(wsum, beta);
    combine_kernel<<<(N_NODES * 32 + 255) / 256, 256, 0, stream>>>(
        (const float4*)z, beta, (float4*)out);
}

// Round 5
// 1909.958 us; speedup vs baseline: 1.6475x; 1.1349x over previous
//
#include <hip/hip_runtime.h>
#include <math.h>

#define N_NODES 100000
#define N_EDGES 500000
#define N_PATHS 3
#define DIM 128
#define K_LAYERS 10
#define NBLK_PER_PATH ((N_NODES + 255) / 256)   // 391

// ---------------- degree histogram, all paths ----------------
__global__ __launch_bounds__(256) void deg_kernel(const int* __restrict__ edges,
                                                  int* __restrict__ degS,
                                                  int* __restrict__ degD) {
    int idx = blockIdx.x * 256 + threadIdx.x;
    if (idx < N_PATHS * N_EDGES) {
        int p = idx / N_EDGES;
        int e = idx - p * N_EDGES;
        const int* src = edges + (size_t)p * 2 * N_EDGES;
        const int* dst = src + N_EDGES;
        atomicAdd(&degS[p * N_NODES + src[e]], 1);
        atomicAdd(&degD[p * N_NODES + dst[e]], 1);
    }
}

// ---------------- normalization factors, all paths ----------------
__global__ __launch_bounds__(256) void norm_kernel(const int* __restrict__ degS,
                                                   const int* __restrict__ degD,
                                                   float* __restrict__ norm_s,
                                                   float* __restrict__ norm_d) {
    int n = blockIdx.x * 256 + threadIdx.x;
    if (n < N_PATHS * N_NODES) {
        norm_s[n] = 1.0f / sqrtf(fmaxf((float)degS[n], 1.0f));
        norm_d[n] = 1.0f / sqrtf(fmaxf((float)degD[n], 1.0f));
    }
}

// ---------------- hierarchical scan: phase A - per-block sums ----------------
__global__ __launch_bounds__(256) void blocksum_kernel(const int* __restrict__ cnt,
                                                       int* __restrict__ bsum) {
    int b = blockIdx.x;                       // p * NBLK_PER_PATH + lb
    int p = b / NBLK_PER_PATH;
    int lb = b - p * NBLK_PER_PATH;
    int idx = lb * 256 + threadIdx.x;
    int v = (idx < N_NODES) ? cnt[p * N_NODES + idx] : 0;
#pragma unroll
    for (int off = 32; off; off >>= 1) v += __shfl_xor(v, off);
    __shared__ int ws[4];
    if ((threadIdx.x & 63) == 0) ws[threadIdx.x >> 6] = v;
    __syncthreads();
    if (threadIdx.x == 0) bsum[b] = ws[0] + ws[1] + ws[2] + ws[3];
}

// ---------------- phase B - scan the 391 block sums per path (3 blocks) --------
__global__ __launch_bounds__(512) void bscan_kernel(int* __restrict__ bsum) {
    __shared__ int s[512];
    int p = blockIdx.x;
    int t = threadIdx.x;
    int v = (t < NBLK_PER_PATH) ? bsum[p * NBLK_PER_PATH + t] : 0;
    s[t] = v;
    __syncthreads();
    for (int off = 1; off < 512; off <<= 1) {
        int x = s[t];
        int a = (t >= off) ? s[t - off] : 0;
        __syncthreads();
        s[t] = x + a;
        __syncthreads();
    }
    if (t < NBLK_PER_PATH) bsum[p * NBLK_PER_PATH + t] = s[t] - v;   // exclusive
}

// ---------------- phase C - block-local rescan + write row_ptr/cursor ----------
__global__ __launch_bounds__(256) void scan_write_kernel(const int* __restrict__ cnt,
                                                         const int* __restrict__ bsum,
                                                         int* __restrict__ row_ptr_all,
                                                         int* __restrict__ cursor_all) {
    __shared__ int s[256];
    int b = blockIdx.x;
    int p = b / NBLK_PER_PATH;
    int lb = b - p * NBLK_PER_PATH;
    int idx = lb * 256 + threadIdx.x;
    int t = threadIdx.x;
    int v = (idx < N_NODES) ? cnt[p * N_NODES + idx] : 0;
    s[t] = v;
    __syncthreads();
    for (int off = 1; off < 256; off <<= 1) {
        int x = s[t];
        int a = (t >= off) ? s[t - off] : 0;
        __syncthreads();
        s[t] = x + a;
        __syncthreads();
    }
    int excl = s[t] - v + bsum[b];
    if (idx < N_NODES) {
        row_ptr_all[p * (N_NODES + 1) + idx] = excl;
        cursor_all[p * N_NODES + idx] = excl;
        if (idx == N_NODES - 1)
            row_ptr_all[p * (N_NODES + 1) + N_NODES] = excl + v;
    }
}

// ---------------- fill CSR: col=src, weight=0.9*norm_s[src]*norm_d[dst] ----------------
__global__ __launch_bounds__(256) void fill_kernel(const int* __restrict__ edges,
                                                   const float* __restrict__ norm_s,
                                                   const float* __restrict__ norm_d,
                                                   int* __restrict__ cursor,
                                                   int2* __restrict__ cw) {
    int idx = blockIdx.x * 256 + threadIdx.x;
    if (idx < N_PATHS * N_EDGES) {
        int p = idx / N_EDGES;
        int e = idx - p * N_EDGES;
        const int* src = edges + (size_t)p * 2 * N_EDGES;
        const int* dst = src + N_EDGES;
        int s = src[e], d = dst[e];
        int pos = atomicAdd(&cursor[p * N_NODES + d], 1);
        float w = 0.9f * norm_s[p * N_NODES + s] * norm_d[p * N_NODES + d];
        cw[(size_t)p * N_EDGES + pos] = make_int2(s, __float_as_int(w));
    }
}

// ---------------- one APPNP layer: one wave per node, scalar edge stream -------
// node forced to SGPR -> row_ptr/cw loads become s_load (broadcast, zero shuffles).
// Lane owns float2: 64 lanes x 8B = full 512B row per gather instruction.
// 4-deep unroll keeps 4 independent gathers in flight.
__global__ __launch_bounds__(256) void prop_kernel(const float2* __restrict__ xsrc,
                                                   const float2* __restrict__ h0,
                                                   float2* __restrict__ xdst,
                                                   const int* __restrict__ row_ptr,
                                                   const int2* __restrict__ cw) {
    int node = __builtin_amdgcn_readfirstlane(blockIdx.x * 4 + (threadIdx.x >> 6));
    int lane = threadIdx.x & 63;
    if (node >= N_NODES) return;
    int beg = row_ptr[node];
    int end = row_ptr[node + 1];
    float2 hv = h0[(size_t)node * 64 + lane];
    float ax = 0.f, ay = 0.f;
    int i = beg;
    for (; i + 4 <= end; i += 4) {
        int2 e0 = cw[i];
        int2 e1 = cw[i + 1];
        int2 e2 = cw[i + 2];
        int2 e3 = cw[i + 3];
        float2 v0 = xsrc[(size_t)e0.x * 64 + lane];
        float2 v1 = xsrc[(size_t)e1.x * 64 + lane];
        float2 v2 = xsrc[(size_t)e2.x * 64 + lane];
        float2 v3 = xsrc[(size_t)e3.x * 64 + lane];
        float w0 = __int_as_float(e0.y), w1 = __int_as_float(e1.y);
        float w2 = __int_as_float(e2.y), w3 = __int_as_float(e3.y);
        ax = fmaf(w0, v0.x, ax); ay = fmaf(w0, v0.y, ay);
        ax = fmaf(w1, v1.x, ax); ay = fmaf(w1, v1.y, ay);
        ax = fmaf(w2, v2.x, ax); ay = fmaf(w2, v2.y, ay);
        ax = fmaf(w3, v3.x, ax); ay = fmaf(w3, v3.y, ay);
    }
    if (i + 2 <= end) {
        int2 e0 = cw[i];
        int2 e1 = cw[i + 1];
        float2 v0 = xsrc[(size_t)e0.x * 64 + lane];
        float2 v1 = xsrc[(size_t)e1.x * 64 + lane];
        float w0 = __int_as_float(e0.y), w1 = __int_as_float(e1.y);
        ax = fmaf(w0, v0.x, ax); ay = fmaf(w0, v0.y, ay);
        ax = fmaf(w1, v1.x, ax); ay = fmaf(w1, v1.y, ay);
        i += 2;
    }
    if (i < end) {
        int2 e = cw[i];
        float2 v = xsrc[(size_t)e.x * 64 + lane];
        float w = __int_as_float(e.y);
        ax = fmaf(w, v.x, ax); ay = fmaf(w, v.y, ay);
    }
    xdst[(size_t)node * 64 + lane] = make_float2(ax + 0.1f * hv.x, ay + 0.1f * hv.y);
}

__device__ __forceinline__ float fast_tanh(float x) {
    float e = __expf(2.0f * x);
    return 1.0f - 2.0f / (e + 1.0f);   // == (e-1)/(e+1) == tanh(x)
}

// ---------------- attention logits: wsum[p] += sum_n tanh(z_row@W1+b1)@w2 ----------------
// Per-wave 8-row z tile staged in private LDS slot via coalesced float4 loads,
// pipelined one tile ahead in registers. Lane owns 4 rows (rh half) x 4 cols (c4).
__global__ __launch_bounds__(256) void attn_kernel(const float* __restrict__ z,
                                                   const float* __restrict__ W1,
                                                   const float* __restrict__ b1,
                                                   const float* __restrict__ w2,
                                                   float* __restrict__ wsum) {
    __shared__ float W1s[DIM * DIM];        // 64 KB
    __shared__ float zt[4][8 * DIM];        // 16 KB, one 8-row tile per wave
    for (int i = threadIdx.x; i < DIM * DIM; i += 256) W1s[i] = W1[i];
    __syncthreads();

    const int wid  = threadIdx.x >> 6;      // 0..3
    const int lane = threadIdx.x & 63;
    const int c4 = (lane & 31) * 4;         // 4-column group base
    const int rh = lane >> 5;               // row half: rows rh*4 .. rh*4+3
    float* myz = zt[wid];

    float4 bias = *(const float4*)(b1 + c4);
    float4 wv   = *(const float4*)(w2 + c4);

    float accP0 = 0.f, accP1 = 0.f, accP2 = 0.f;
    const int NTILES = N_PATHS * N_NODES / 8;   // 37500
    const int TPP = N_NODES / 8;                // 12500 tiles per path
    const int tstride = gridDim.x * 4;

    int t = blockIdx.x * 4 + wid;
    float4 pre0, pre1, pre2, pre3;
    if (t < NTILES) {
        const float4* g = (const float4*)(z + (size_t)t * 8 * DIM);
        pre0 = g[lane]; pre1 = g[64 + lane]; pre2 = g[128 + lane]; pre3 = g[192 + lane];
    }
    for (; t < NTILES; t += tstride) {
        *(float4*)&myz[lane * 4]              = pre0;
        *(float4*)&myz[(64 + lane) * 4]       = pre1;
        *(float4*)&myz[(128 + lane) * 4]      = pre2;
        *(float4*)&myz[(192 + lane) * 4]      = pre3;
        asm volatile("s_waitcnt lgkmcnt(0)" ::: "memory");
        int tn = t + tstride;
        if (tn < NTILES) {
            const float4* g = (const float4*)(z + (size_t)tn * 8 * DIM);
            pre0 = g[lane]; pre1 = g[64 + lane]; pre2 = g[128 + lane]; pre3 = g[192 + lane];
        }
        float acc[4][4];
#pragma unroll
        for (int r = 0; r < 4; ++r)
#pragma unroll
            for (int j = 0; j < 4; ++j) acc[r][j] = 0.f;

        for (int k = 0; k < DIM; k += 4) {
            float4 w0 = *(const float4*)&W1s[(k + 0) * DIM + c4];
            float4 w1_ = *(const float4*)&W1s[(k + 1) * DIM + c4];
            float4 w2_ = *(const float4*)&W1s[(k + 2) * DIM + c4];
            float4 w3_ = *(const float4*)&W1s[(k + 3) * DIM + c4];
#pragma unroll
            for (int r = 0; r < 4; ++r) {
                float4 zv = *(const float4*)&myz[(rh * 4 + r) * DIM + k];
                acc[r][0] = fmaf(zv.x, w0.x, acc[r][0]);
                acc[r][1] = fmaf(zv.x, w0.y, acc[r][1]);
                acc[r][2] = fmaf(zv.x, w0.z, acc[r][2]);
                acc[r][3] = fmaf(zv.x, w0.w, acc[r][3]);
                acc[r][0] = fmaf(zv.y, w1_.x, acc[r][0]);
                acc[r][1] = fmaf(zv.y, w1_.y, acc[r][1]);
                acc[r][2] = fmaf(zv.y, w1_.z, acc[r][2]);
                acc[r][3] = fmaf(zv.y, w1_.w, acc[r][3]);
                acc[r][0] = fmaf(zv.z, w2_.x, acc[r][0]);
                acc[r][1] = fmaf(zv.z, w2_.y, acc[r][1]);
                acc[r][2] = fmaf(zv.z, w2_.z, acc[r][2]);
                acc[r][3] = fmaf(zv.z, w2_.w, acc[r][3]);
                acc[r][0] = fmaf(zv.w, w3_.x, acc[r][0]);
                acc[r][1] = fmaf(zv.w, w3_.y, acc[r][1]);
                acc[r][2] = fmaf(zv.w, w3_.z, acc[r][2]);
                acc[r][3] = fmaf(zv.w, w3_.w, acc[r][3]);
            }
        }
        float psum = 0.f;
#pragma unroll
        for (int r = 0; r < 4; ++r) {
            psum += fast_tanh(acc[r][0] + bias.x) * wv.x;
            psum += fast_tanh(acc[r][1] + bias.y) * wv.y;
            psum += fast_tanh(acc[r][2] + bias.z) * wv.z;
            psum += fast_tanh(acc[r][3] + bias.w) * wv.w;
        }
#pragma unroll
        for (int off = 32; off; off >>= 1) psum += __shfl_xor(psum, off);
        if (lane == 0) {
            int p = t / TPP;
            if (p == 0) accP0 += psum;
            else if (p == 1) accP1 += psum;
            else accP2 += psum;
        }
    }
    if (lane == 0) {
        if (accP0 != 0.f) atomicAdd(&wsum[0], accP0);
        if (accP1 != 0.f) atomicAdd(&wsum[1], accP1);
        if (accP2 != 0.f) atomicAdd(&wsum[2], accP2);
    }
}

// ---------------- beta = softmax(wsum / N) over 3 paths ----------------
__global__ void beta_kernel(const float* __restrict__ wsum, float* __restrict__ beta) {
    if (threadIdx.x == 0 && blockIdx.x == 0) {
        float w0 = wsum[0] * (1.0f / N_NODES);
        float w1 = wsum[1] * (1.0f / N_NODES);
        float w2v = wsum[2] * (1.0f / N_NODES);
        float m = fmaxf(w0, fmaxf(w1, w2v));
        float e0 = expf(w0 - m), e1 = expf(w1 - m), e2 = expf(w2v - m);
        float inv = 1.0f / (e0 + e1 + e2);
        beta[0] = e0 * inv;
        beta[1] = e1 * inv;
        beta[2] = e2 * inv;
    }
}

// ---------------- out[n,:] = sum_p beta[p] * z[p,n,:] ----------------
__global__ __launch_bounds__(256) void combine_kernel(const float4* __restrict__ z4,
                                                      const float* __restrict__ beta,
                                                      float4* __restrict__ out4) {
    size_t idx = (size_t)blockIdx.x * 256 + threadIdx.x;
    const size_t M = (size_t)N_NODES * 32;
    if (idx < M) {
        float b0 = beta[0], b1 = beta[1], b2 = beta[2];
        float4 a = z4[idx];
        float4 b = z4[M + idx];
        float4 c = z4[2 * M + idx];
        float4 o;
        o.x = b0 * a.x + b1 * b.x + b2 * c.x;
        o.y = b0 * a.y + b1 * b.y + b2 * c.y;
        o.z = b0 * a.z + b1 * b.z + b2 * c.z;
        o.w = b0 * a.w + b1 * b.w + b2 * c.w;
        out4[idx] = o;
    }
}

extern "C" void kernel_launch(void* const* d_in, const int* in_sizes, int n_in,
                              void* d_out, int out_size, void* d_ws, size_t ws_size,
                              hipStream_t stream) {
    const float* h     = (const float*)d_in[0];
    const int*   edges = (const int*)d_in[1];   // (3, 2, 500000) int32
    const float* W1    = (const float*)d_in[2];
    const float* b1    = (const float*)d_in[3];
    const float* w2    = (const float*)d_in[4];
    float* out = (float*)d_out;

    // ---- workspace carve (8B-aligned) ----
    char* ws = (char*)d_ws;
    float* z = (float*)ws;       ws += (size_t)N_PATHS * N_NODES * DIM * 4;   // 153.6 MB
    float* xb = (float*)ws;      ws += (size_t)N_NODES * DIM * 4;             // 51.2 MB
    int2* cw = (int2*)ws;        ws += (size_t)N_PATHS * N_EDGES * 8;         // 12 MB
    int* row_ptr = (int*)ws;     ws += (size_t)N_PATHS * (N_NODES + 1) * 4 + 8;
    int* cursor = (int*)ws;      ws += (size_t)N_PATHS * N_NODES * 4;
    float* norm_s = (float*)ws;  ws += (size_t)N_PATHS * N_NODES * 4;
    float* norm_d = (float*)ws;  ws += (size_t)N_PATHS * N_NODES * 4;
    int* degS = (int*)ws;        ws += (size_t)N_PATHS * N_NODES * 4;
    int* degD = (int*)ws;        ws += (size_t)N_PATHS * N_NODES * 4;  // adjacent to degS
    int* bsum = (int*)ws;        ws += (size_t)N_PATHS * NBLK_PER_PATH * 4;
    float* wsum = (float*)ws;    ws += 4 * 4;
    float* beta = (float*)ws;    ws += 4 * 4;

    // ---- CSR build, all 3 paths batched ----
    hipMemsetAsync(degS, 0, (size_t)2 * N_PATHS * N_NODES * 4, stream);
    deg_kernel<<<(N_PATHS * N_EDGES + 255) / 256, 256, 0, stream>>>(edges, degS, degD);
    norm_kernel<<<(N_PATHS * N_NODES + 255) / 256, 256, 0, stream>>>(degS, degD, norm_s, norm_d);
    blocksum_kernel<<<N_PATHS * NBLK_PER_PATH, 256, 0, stream>>>(degD, bsum);
    bscan_kernel<<<N_PATHS, 512, 0, stream>>>(bsum);
    scan_write_kernel<<<N_PATHS * NBLK_PER_PATH, 256, 0, stream>>>(degD, bsum, row_ptr, cursor);
    fill_kernel<<<(N_PATHS * N_EDGES + 255) / 256, 256, 0, stream>>>(edges, norm_s, norm_d, cursor, cw);

    // ---- APPNP propagation, per path (keeps L3 working set ~150 MB) ----
    for (int p = 0; p < N_PATHS; ++p) {
        float* zp = z + (size_t)p * N_NODES * DIM;
        const int* rp = row_ptr + (size_t)p * (N_NODES + 1);
        const int2* cwp = cw + (size_t)p * N_EDGES;
        for (int i = 0; i < K_LAYERS; ++i) {
            // i even -> write xb, i odd -> write zp; layer 9 (last) lands in zp
            const float* s = (i == 0) ? h : ((i & 1) ? xb : zp);
            float* dbuf = (i & 1) ? zp : xb;
            prop_kernel<<<(N_NODES + 3) / 4, 256, 0, stream>>>(
                (const float2*)s, (const float2*)h, (float2*)dbuf, rp, cwp);
        }
    }

    // ---- semantic attention ----
    hipMemsetAsync(wsum, 0, 3 * 4, stream);
    attn_kernel<<<1024, 256, 0, stream>>>(z, W1, b1, w2, wsum);
    beta_kernel<<<1, 64, 0, stream>>>(wsum, beta);
    combine_kernel<<<(N_NODES * 32 + 255) / 256, 256, 0, stream>>>(
        (const float4*)z, beta, (float4*)out);
}